// Round 3
// baseline (1559.772 us; speedup 1.0000x reference)
//
#include <hip/hip_runtime.h>
#include <math.h>

#define D 64
#define MIN_NORM 1e-15f
#define PROJ_MAXNORM 0.996f   // (1 - 4e-3) / sqrt(c), c=1

__device__ __forceinline__ float wave_reduce_sum(float v) {
#pragma unroll
    for (int m = 1; m < 64; m <<= 1)
        v += __shfl_xor(v, m, 64);
    return v;
}

__device__ __forceinline__ float artanh_clip(float z) {
    z = fminf(z, 1.0f - 1e-7f);
    z = fmaxf(z, -1.0f + 1e-7f);
    return 0.5f * logf((1.0f + z) / (1.0f - z));
}

// Kernel A: per-node squared norm + logmap0 scale factor; init rowsum to 1e-10.
__global__ void prep_kernel(const float* __restrict__ x,
                            float* __restrict__ sn,
                            float* __restrict__ f,
                            float* __restrict__ rowsum,
                            int N) {
    int node = blockIdx.x * 4 + (threadIdx.x >> 6);
    int lane = threadIdx.x & 63;
    if (node >= N) return;
    float v = x[node * D + lane];
    float s = wave_reduce_sum(v * v);
    if (lane == 0) {
        sn[node] = s;
        float pn = fmaxf(sqrtf(s), MIN_NORM);
        f[node] = artanh_clip(pn) / pn;
        rowsum[node] = 1e-10f;
    }
}

// Kernel B: 16 lanes per edge (4 edges per wave), float4 loads.
// Per-edge cost amortized 4x across the wave vs wave-per-edge layout.
__global__ void edge_kernel(const float* __restrict__ x,
                            const float* __restrict__ sn,
                            const float* __restrict__ f,
                            const int* __restrict__ row_idx,
                            const int* __restrict__ col_idx,
                            const float* __restrict__ beta,
                            const float* __restrict__ con,
                            float* __restrict__ support,
                            float* __restrict__ rowsum,
                            int E) {
    int t = blockIdx.x * 256 + threadIdx.x;
    int e = t >> 4;            // one edge per 16 lanes
    if (e >= E) return;
    int q = t & 15;            // sub-lane within the edge group

    int r = row_idx[e];
    int c = col_idx[e];

    const float4* x4 = (const float4*)x;
    float4 ar = x4[r * 16 + q];
    float4 ac = x4[c * 16 + q];

    // dot(p1,p2): per-lane float4 dot, then 4-step reduce across the 16 lanes
    float d = ar.x * ac.x + ar.y * ac.y + ar.z * ac.z + ar.w * ac.w;
#pragma unroll
    for (int m = 1; m < 16; m <<= 1)
        d += __shfl_xor(d, m, 64);   // xor stays within the 16-lane group

    float x2 = sn[r];
    float y2 = sn[c];
    // mobius_add(-p1, p2): num = -a*p1 + b*p2
    float a = 1.0f - 2.0f * d + y2;
    float b = 1.0f - x2;
    float num2 = a * a * x2 - 2.0f * a * b * d + b * b * y2;
    float denom = fmaxf(1.0f - 2.0f * d + x2 * y2, MIN_NORM);
    float man = sqrtf(fmaxf(num2, 0.0f)) / denom;
    float dist = 2.0f * artanh_clip(man);
    float w = expf(-beta[0] * dist * dist + con[0]);

    // x_t[col] = f[col] * x[col] (reuse loaded ac)
    float s = w * f[c];
    float* sp = support + (size_t)r * D + q * 4;
    unsafeAtomicAdd(sp + 0, s * ac.x);
    unsafeAtomicAdd(sp + 1, s * ac.y);
    unsafeAtomicAdd(sp + 2, s * ac.z);
    unsafeAtomicAdd(sp + 3, s * ac.w);
    if (q == 0) unsafeAtomicAdd(&rowsum[r], w);
}

// Kernel C: in-place finalize: support/rowsum -> expmap0 -> proj
__global__ void final_kernel(float* __restrict__ out,
                             const float* __restrict__ rowsum,
                             int N) {
    int node = blockIdx.x * 4 + (threadIdx.x >> 6);
    int lane = threadIdx.x & 63;
    if (node >= N) return;
    float s = out[node * D + lane] / rowsum[node];  // rowsum already includes 1e-10
    float n2 = wave_reduce_sum(s * s);
    float un = fmaxf(sqrtf(n2), MIN_NORM);
    float t = tanhf(un) / un;   // expmap0 scale
    float o = t * s;
    float on = t * sqrtf(n2);   // ||o||
    if (on > PROJ_MAXNORM)
        o = o / fmaxf(on, MIN_NORM) * PROJ_MAXNORM;
    out[node * D + lane] = o;
}

extern "C" void kernel_launch(void* const* d_in, const int* in_sizes, int n_in,
                              void* d_out, int out_size, void* d_ws, size_t ws_size,
                              hipStream_t stream) {
    const float* x    = (const float*)d_in[0];
    const float* beta = (const float*)d_in[1];
    const float* con  = (const float*)d_in[2];
    const int*   ei   = (const int*)d_in[3];

    int N = in_sizes[0] / D;
    int E = in_sizes[3] / 2;
    const int* row_idx = ei;
    const int* col_idx = ei + E;

    float* out = (float*)d_out;
    float* sn     = (float*)d_ws;           // N floats
    float* f      = sn + N;                 // N floats
    float* rowsum = f + N;                  // N floats

    // support accumulates directly in d_out; must be zeroed (harness poisons 0xAA)
    hipMemsetAsync(d_out, 0, (size_t)N * D * sizeof(float), stream);

    int nodeBlocks = (N + 3) / 4;
    prep_kernel<<<nodeBlocks, 256, 0, stream>>>(x, sn, f, rowsum, N);

    // 16 lanes per edge -> 16 edges per 256-thread block
    int edgeBlocks = (E + 15) / 16;
    edge_kernel<<<edgeBlocks, 256, 0, stream>>>(x, sn, f, row_idx, col_idx,
                                                beta, con, out, rowsum, E);

    final_kernel<<<nodeBlocks, 256, 0, stream>>>(out, rowsum, N);
}

// Round 4
// 410.743 us; speedup vs baseline: 3.7974x; 3.7974x over previous
//
#include <hip/hip_runtime.h>
#include <math.h>

#define D 64
#define MIN_NORM 1e-15f
#define PROJ_MAXNORM 0.996f   // (1 - 4e-3) / sqrt(c), c=1
#define SCAN_T 1024

__device__ __forceinline__ float wave_reduce_sum(float v) {
#pragma unroll
    for (int m = 1; m < 64; m <<= 1)
        v += __shfl_xor(v, m, 64);
    return v;
}

// artanh for z >= 0 (input is a norm), fast log + rcp
__device__ __forceinline__ float fast_artanh(float z) {
    z = fminf(z, 1.0f - 1e-7f);
    return 0.5f * __logf((1.0f + z) * __builtin_amdgcn_rcpf(1.0f - z));
}

// Kernel 1: per-node squared norm sn, tangent features x_t = logmap0(x)
__global__ void prep_kernel(const float* __restrict__ x,
                            float* __restrict__ x_t,
                            float* __restrict__ sn,
                            int N) {
    int node = blockIdx.x * 4 + (threadIdx.x >> 6);
    int lane = threadIdx.x & 63;
    if (node >= N) return;
    float v = x[node * D + lane];
    float s = wave_reduce_sum(v * v);
    float pn = fmaxf(sqrtf(s), MIN_NORM);
    float f = fast_artanh(pn) / pn;
    x_t[node * D + lane] = f * v;
    if (lane == 0) sn[node] = s;
}

// Kernel 2: histogram of row indices (int atomics, native+fast)
__global__ void count_kernel(const int* __restrict__ row_idx,
                             int* __restrict__ count, int E) {
    int e = blockIdx.x * 256 + threadIdx.x;
    if (e < E) atomicAdd(&count[row_idx[e]], 1);
}

// Kernel 3a: per-block exclusive scan, block totals to bsums
__global__ void scan1_kernel(const int* __restrict__ in,
                             int* __restrict__ out,
                             int* __restrict__ bsums, int N) {
    __shared__ int tmp[SCAN_T];
    int tid = threadIdx.x, gid = blockIdx.x * SCAN_T + tid;
    int v = (gid < N) ? in[gid] : 0;
    tmp[tid] = v;
    __syncthreads();
    for (int off = 1; off < SCAN_T; off <<= 1) {
        int t = (tid >= off) ? tmp[tid - off] : 0;
        __syncthreads();
        tmp[tid] += t;
        __syncthreads();
    }
    if (gid < N) out[gid] = tmp[tid] - v;          // exclusive
    if (tid == SCAN_T - 1) bsums[blockIdx.x] = tmp[tid];  // inclusive total
}

// Kernel 3b: single-block exclusive scan of block totals
__global__ void scan2_kernel(const int* __restrict__ bsums,
                             int* __restrict__ boffs, int B) {
    __shared__ int tmp[SCAN_T];
    int tid = threadIdx.x;
    int v = (tid < B) ? bsums[tid] : 0;
    tmp[tid] = v;
    __syncthreads();
    for (int off = 1; off < SCAN_T; off <<= 1) {
        int t = (tid >= off) ? tmp[tid - off] : 0;
        __syncthreads();
        tmp[tid] += t;
        __syncthreads();
    }
    if (tid < B) boffs[tid] = tmp[tid] - v;
}

// Kernel 3c: add block offsets -> row_start; init cursor; row_start[N]=E
__global__ void scan3_kernel(int* __restrict__ row_start,
                             int* __restrict__ cursor,
                             const int* __restrict__ boffs, int N, int E) {
    int gid = blockIdx.x * SCAN_T + threadIdx.x;
    if (gid < N) {
        int v = row_start[gid] + boffs[blockIdx.x];
        row_start[gid] = v;
        cursor[gid] = v;
    }
    if (gid == 0) row_start[N] = E;
}

// Kernel 4: 16 lanes per edge (4 edges/wave): compute attention weight w,
// place packed (w, col) into CSR slot via one int atomic per edge.
__global__ void scatter_kernel(const float* __restrict__ x,
                               const float* __restrict__ sn,
                               const int* __restrict__ row_idx,
                               const int* __restrict__ col_idx,
                               const float* __restrict__ beta,
                               const float* __restrict__ con,
                               int* __restrict__ cursor,
                               float2* __restrict__ wc, int E) {
    int t = blockIdx.x * 256 + threadIdx.x;
    int e = t >> 4;
    if (e >= E) return;
    int q = t & 15;
    int r = row_idx[e];
    int c = col_idx[e];
    const float4* x4 = (const float4*)x;
    float4 ar = x4[r * 16 + q];
    float4 ac = x4[c * 16 + q];
    float d = ar.x * ac.x + ar.y * ac.y + ar.z * ac.z + ar.w * ac.w;
#pragma unroll
    for (int m = 1; m < 16; m <<= 1)
        d += __shfl_xor(d, m, 64);
    float x2 = sn[r];
    float y2 = sn[c];
    float a = 1.0f - 2.0f * d + y2;
    float b = 1.0f - x2;
    float num2 = a * a * x2 - 2.0f * a * b * d + b * b * y2;
    float den = fmaxf(1.0f - 2.0f * d + x2 * y2, MIN_NORM);
    float man = sqrtf(fmaxf(num2, 0.0f)) * __builtin_amdgcn_rcpf(den);
    float at = fast_artanh(man);
    float w = __expf(-beta[0] * 4.0f * at * at + con[0]);  // dist^2 = 4*artanh^2
    if (q == 0) {
        int pos = atomicAdd(&cursor[r], 1);
        wc[pos] = make_float2(w, __int_as_float(c));
    }
}

// Kernel 5: wave-per-row gather-aggregate + fused expmap0/proj epilogue.
__global__ void aggregate_kernel(const float* __restrict__ x_t,
                                 const float2* __restrict__ wc,
                                 const int* __restrict__ row_start,
                                 float* __restrict__ out, int N) {
    int row = blockIdx.x * 4 + (threadIdx.x >> 6);
    int lane = threadIdx.x & 63;
    if (row >= N) return;
    int start = row_start[row];
    int end = row_start[row + 1];
    float acc = 0.0f, wsum = 0.0f;
    for (int j0 = start; j0 < end; j0 += 64) {
        int n = min(64, end - j0);
        float2 v = make_float2(0.0f, 0.0f);
        if (lane < n) v = wc[j0 + lane];          // coalesced chunk load
        for (int k = 0; k < n; k++) {
            float w = __shfl(v.x, k, 64);
            int c = __float_as_int(__shfl(v.y, k, 64));
            acc += w * x_t[c * D + lane];          // coalesced 256B gather
            wsum += w;
        }
    }
    float s = acc / (wsum + 1e-10f);
    float n2 = wave_reduce_sum(s * s);
    float un = fmaxf(sqrtf(n2), MIN_NORM);
    float tt = tanhf(un) / un;                     // expmap0 scale
    float o = tt * s;
    float on = tt * sqrtf(n2);                     // ||o||
    if (on > PROJ_MAXNORM)
        o = o / fmaxf(on, MIN_NORM) * PROJ_MAXNORM;
    out[row * D + lane] = o;
}

extern "C" void kernel_launch(void* const* d_in, const int* in_sizes, int n_in,
                              void* d_out, int out_size, void* d_ws, size_t ws_size,
                              hipStream_t stream) {
    const float* x    = (const float*)d_in[0];
    const float* beta = (const float*)d_in[1];
    const float* con  = (const float*)d_in[2];
    const int*   ei   = (const int*)d_in[3];

    int N = in_sizes[0] / D;
    int E = in_sizes[3] / 2;
    const int* row_idx = ei;
    const int* col_idx = ei + E;
    float* out = (float*)d_out;

    // workspace layout (8B-aligned first)
    float2* wc       = (float2*)d_ws;                    // E float2 (12.8 MB)
    float*  x_t      = (float*)(wc + E);                 // N*D floats (25.6 MB)
    float*  sn       = x_t + (size_t)N * D;              // N floats
    int*    count    = (int*)(sn + N);                   // N ints
    int*    row_start= count + N;                        // N+1 ints
    int*    cursor   = row_start + N + 1;                // N ints
    int*    bsums    = cursor + N;                       // SCAN_T ints
    int*    boffs    = bsums + SCAN_T;                   // SCAN_T ints

    hipMemsetAsync(count, 0, (size_t)N * sizeof(int), stream);

    int nodeBlocks = (N + 3) / 4;
    prep_kernel<<<nodeBlocks, 256, 0, stream>>>(x, x_t, sn, N);

    count_kernel<<<(E + 255) / 256, 256, 0, stream>>>(row_idx, count, E);

    int SB = (N + SCAN_T - 1) / SCAN_T;   // 98 blocks for N=100K
    scan1_kernel<<<SB, SCAN_T, 0, stream>>>(count, row_start, bsums, N);
    scan2_kernel<<<1, SCAN_T, 0, stream>>>(bsums, boffs, SB);
    scan3_kernel<<<SB, SCAN_T, 0, stream>>>(row_start, cursor, boffs, N, E);

    scatter_kernel<<<(E + 15) / 16, 256, 0, stream>>>(x, sn, row_idx, col_idx,
                                                      beta, con, cursor, wc, E);

    aggregate_kernel<<<nodeBlocks, 256, 0, stream>>>(x_t, wc, row_start, out, N);
}

// Round 5
// 377.114 us; speedup vs baseline: 4.1361x; 1.0892x over previous
//
#include <hip/hip_runtime.h>
#include <math.h>

#define D 64
#define MIN_NORM 1e-15f
#define PROJ_MAXNORM 0.996f   // (1 - 4e-3) / sqrt(c), c=1
#define SCAN_T 1024

__device__ __forceinline__ float wave_reduce_sum(float v) {
#pragma unroll
    for (int m = 1; m < 64; m <<= 1)
        v += __shfl_xor(v, m, 64);
    return v;
}

// artanh for z >= 0 (input is a norm), fast log + rcp
__device__ __forceinline__ float fast_artanh(float z) {
    z = fminf(z, 1.0f - 1e-7f);
    return 0.5f * __logf((1.0f + z) * __builtin_amdgcn_rcpf(1.0f - z));
}

__device__ __forceinline__ unsigned short f2bf(float x) {  // RNE
    unsigned int b = __float_as_uint(x);
    return (unsigned short)((b + 0x7fffu + ((b >> 16) & 1u)) >> 16);
}

__device__ __forceinline__ float bf2f(unsigned short u) {
    return __uint_as_float(((unsigned int)u) << 16);
}

// Kernel 1: per-node squared norm sn, bf16 copy of x, bf16 tangent features
__global__ void prep_kernel(const float* __restrict__ x,
                            unsigned short* __restrict__ x_bf,
                            unsigned short* __restrict__ xt_bf,
                            float* __restrict__ sn,
                            int N) {
    int node = blockIdx.x * 4 + (threadIdx.x >> 6);
    int lane = threadIdx.x & 63;
    if (node >= N) return;
    float v = x[node * D + lane];
    float s = wave_reduce_sum(v * v);
    float pn = fmaxf(sqrtf(s), MIN_NORM);
    float f = fast_artanh(pn) / pn;
    x_bf[node * D + lane]  = f2bf(v);
    xt_bf[node * D + lane] = f2bf(f * v);
    if (lane == 0) sn[node] = s;
}

// Kernel 2: histogram of row indices (int atomics, native+fast)
__global__ void count_kernel(const int* __restrict__ row_idx,
                             int* __restrict__ count, int E) {
    int e = blockIdx.x * 256 + threadIdx.x;
    if (e < E) atomicAdd(&count[row_idx[e]], 1);
}

// Kernel 3a: per-block exclusive scan, block totals to bsums
__global__ void scan1_kernel(const int* __restrict__ in,
                             int* __restrict__ out,
                             int* __restrict__ bsums, int N) {
    __shared__ int tmp[SCAN_T];
    int tid = threadIdx.x, gid = blockIdx.x * SCAN_T + tid;
    int v = (gid < N) ? in[gid] : 0;
    tmp[tid] = v;
    __syncthreads();
    for (int off = 1; off < SCAN_T; off <<= 1) {
        int t = (tid >= off) ? tmp[tid - off] : 0;
        __syncthreads();
        tmp[tid] += t;
        __syncthreads();
    }
    if (gid < N) out[gid] = tmp[tid] - v;          // exclusive
    if (tid == SCAN_T - 1) bsums[blockIdx.x] = tmp[tid];  // inclusive total
}

// Kernel 3b: single-block exclusive scan of block totals
__global__ void scan2_kernel(const int* __restrict__ bsums,
                             int* __restrict__ boffs, int B) {
    __shared__ int tmp[SCAN_T];
    int tid = threadIdx.x;
    int v = (tid < B) ? bsums[tid] : 0;
    tmp[tid] = v;
    __syncthreads();
    for (int off = 1; off < SCAN_T; off <<= 1) {
        int t = (tid >= off) ? tmp[tid - off] : 0;
        __syncthreads();
        tmp[tid] += t;
        __syncthreads();
    }
    if (tid < B) boffs[tid] = tmp[tid] - v;
}

// Kernel 3c: add block offsets -> row_start; init cursor; row_start[N]=E
__global__ void scan3_kernel(int* __restrict__ row_start,
                             int* __restrict__ cursor,
                             const int* __restrict__ boffs, int N, int E) {
    int gid = blockIdx.x * SCAN_T + threadIdx.x;
    if (gid < N) {
        int v = row_start[gid] + boffs[blockIdx.x];
        row_start[gid] = v;
        cursor[gid] = v;
    }
    if (gid == 0) row_start[N] = E;
}

// Kernel 4: 16 lanes per edge (4 edges/wave). bf16 rows: 16 lanes x ushort4
// = 128B per row (half the fp32 traffic). One int atomic per edge -> CSR slot.
__global__ void scatter_kernel(const unsigned short* __restrict__ x_bf,
                               const float* __restrict__ sn,
                               const int* __restrict__ row_idx,
                               const int* __restrict__ col_idx,
                               const float* __restrict__ beta,
                               const float* __restrict__ con,
                               int* __restrict__ cursor,
                               float2* __restrict__ wc, int E) {
    int t = blockIdx.x * 256 + threadIdx.x;
    int e = t >> 4;
    if (e >= E) return;
    int q = t & 15;
    int r = row_idx[e];
    int c = col_idx[e];
    const ushort4* x4 = (const ushort4*)x_bf;   // 64 bf16 = 16 x ushort4
    ushort4 ar = x4[r * 16 + q];
    ushort4 ac = x4[c * 16 + q];
    float d = bf2f(ar.x) * bf2f(ac.x) + bf2f(ar.y) * bf2f(ac.y)
            + bf2f(ar.z) * bf2f(ac.z) + bf2f(ar.w) * bf2f(ac.w);
#pragma unroll
    for (int m = 1; m < 16; m <<= 1)
        d += __shfl_xor(d, m, 64);
    float x2 = sn[r];
    float y2 = sn[c];
    float a = 1.0f - 2.0f * d + y2;
    float b = 1.0f - x2;
    float num2 = a * a * x2 - 2.0f * a * b * d + b * b * y2;
    float den = fmaxf(1.0f - 2.0f * d + x2 * y2, MIN_NORM);
    float man = sqrtf(fmaxf(num2, 0.0f)) * __builtin_amdgcn_rcpf(den);
    float at = fast_artanh(man);
    float w = __expf(-beta[0] * 4.0f * at * at + con[0]);  // dist^2 = 4*artanh^2
    if (q == 0) {
        int pos = atomicAdd(&cursor[r], 1);
        wc[pos] = make_float2(w, __int_as_float(c));
    }
}

// Kernel 5: wave-per-row gather-aggregate (bf16 x_t rows, 128B/edge)
// + fused expmap0/proj epilogue.
__global__ void aggregate_kernel(const unsigned short* __restrict__ xt_bf,
                                 const float2* __restrict__ wc,
                                 const int* __restrict__ row_start,
                                 float* __restrict__ out, int N) {
    int row = blockIdx.x * 4 + (threadIdx.x >> 6);
    int lane = threadIdx.x & 63;
    if (row >= N) return;
    int start = row_start[row];
    int end = row_start[row + 1];
    float acc = 0.0f, wsum = 0.0f;
    for (int j0 = start; j0 < end; j0 += 64) {
        int n = min(64, end - j0);
        float2 v = make_float2(0.0f, 0.0f);
        if (lane < n) v = wc[j0 + lane];          // coalesced chunk load
        for (int k = 0; k < n; k++) {
            float w = __shfl(v.x, k, 64);
            int c = __float_as_int(__shfl(v.y, k, 64));
            acc += w * bf2f(xt_bf[c * D + lane]);  // coalesced 128B gather
            wsum += w;
        }
    }
    float s = acc / (wsum + 1e-10f);
    float n2 = wave_reduce_sum(s * s);
    float un = fmaxf(sqrtf(n2), MIN_NORM);
    float tt = tanhf(un) / un;                     // expmap0 scale
    float o = tt * s;
    float on = tt * sqrtf(n2);                     // ||o||
    if (on > PROJ_MAXNORM)
        o = o / fmaxf(on, MIN_NORM) * PROJ_MAXNORM;
    out[row * D + lane] = o;
}

extern "C" void kernel_launch(void* const* d_in, const int* in_sizes, int n_in,
                              void* d_out, int out_size, void* d_ws, size_t ws_size,
                              hipStream_t stream) {
    const float* x    = (const float*)d_in[0];
    const float* beta = (const float*)d_in[1];
    const float* con  = (const float*)d_in[2];
    const int*   ei   = (const int*)d_in[3];

    int N = in_sizes[0] / D;
    int E = in_sizes[3] / 2;
    const int* row_idx = ei;
    const int* col_idx = ei + E;
    float* out = (float*)d_out;

    // workspace layout (8B-aligned first)
    float2*         wc    = (float2*)d_ws;                 // E float2 (12.8 MB)
    unsigned short* x_bf  = (unsigned short*)(wc + E);     // N*D bf16 (12.8 MB)
    unsigned short* xt_bf = x_bf + (size_t)N * D;          // N*D bf16 (12.8 MB)
    float*  sn       = (float*)(xt_bf + (size_t)N * D);    // N floats
    int*    count    = (int*)(sn + N);                     // N ints
    int*    row_start= count + N;                          // N+1 ints
    int*    cursor   = row_start + N + 1;                  // N ints
    int*    bsums    = cursor + N;                         // SCAN_T ints
    int*    boffs    = bsums + SCAN_T;                     // SCAN_T ints

    hipMemsetAsync(count, 0, (size_t)N * sizeof(int), stream);

    int nodeBlocks = (N + 3) / 4;
    prep_kernel<<<nodeBlocks, 256, 0, stream>>>(x, x_bf, xt_bf, sn, N);

    count_kernel<<<(E + 255) / 256, 256, 0, stream>>>(row_idx, count, E);

    int SB = (N + SCAN_T - 1) / SCAN_T;   // 98 blocks for N=100K
    scan1_kernel<<<SB, SCAN_T, 0, stream>>>(count, row_start, bsums, N);
    scan2_kernel<<<1, SCAN_T, 0, stream>>>(bsums, boffs, SB);
    scan3_kernel<<<SB, SCAN_T, 0, stream>>>(row_start, cursor, boffs, N, E);

    scatter_kernel<<<(E + 15) / 16, 256, 0, stream>>>(x_bf, sn, row_idx, col_idx,
                                                      beta, con, cursor, wc, E);

    aggregate_kernel<<<nodeBlocks, 256, 0, stream>>>(xt_bf, wc, row_start, out, N);
}